// Round 1
// baseline (286.761 us; speedup 1.0000x reference)
//
#include <hip/hip_runtime.h>
#include <math.h>

#define N_ROWS 16384
#define DIM 4096
#define NEXP 64
#define ROWS_PER_BLOCK 32
#define ROWS_PER_WAVE 8
#define WAVES_PER_BLOCK 4
#define DT 128                 // d-tile depth
#define NT (DIM / DT)          // 32 tiles

// lane = expert. Wave owns 8 rows; acc[r] holds score[row r][expert=lane].
// W tile staged transposed+swizzled in LDS: wt[d*64 + (e ^ ((d>>2)&31))].
// x tile staged as float4 rows; main-loop x reads are wave-uniform (broadcast).
__global__ __launch_bounds__(256, 2)
void gate_kernel(const float* __restrict__ x, const float* __restrict__ w,
                 float* __restrict__ out)
{
    __shared__ float  wt[DT * NEXP];                     // 32 KB
    __shared__ float4 xs[ROWS_PER_BLOCK * (DT / 4)];     // 16 KB

    const int tid  = threadIdx.x;
    const int lane = tid & 63;
    const int wv   = tid >> 6;                 // 0..3
    const int row0 = blockIdx.x * ROWS_PER_BLOCK;
    const int wrow0 = wv * ROWS_PER_WAVE;

    float acc[ROWS_PER_WAVE];
#pragma unroll
    for (int r = 0; r < ROWS_PER_WAVE; ++r) acc[r] = 0.f;

    for (int t = 0; t < NT; ++t) {
        const int d0 = t * DT;
        __syncthreads();
        // ---- stage W tile: 64 experts x 128 d = 2048 float4, 8 per thread ----
#pragma unroll
        for (int i = 0; i < 8; ++i) {
            int g  = i * 256 + tid;
            int e  = g >> 5;          // 0..63
            int d4 = g & 31;          // 0..31  (== (d>>2) since DT=128)
            float4 v = *reinterpret_cast<const float4*>(&w[e * DIM + d0 + 4 * d4]);
            int col = e ^ d4;         // XOR swizzle keeps both write & read conflict-free
            wt[(4 * d4 + 0) * 64 + col] = v.x;
            wt[(4 * d4 + 1) * 64 + col] = v.y;
            wt[(4 * d4 + 2) * 64 + col] = v.z;
            wt[(4 * d4 + 3) * 64 + col] = v.w;
        }
        // ---- stage x tile: 32 rows x 128 d = 1024 float4, 4 per thread ----
#pragma unroll
        for (int i = 0; i < 4; ++i) {
            int g  = i * 256 + tid;
            int r  = g >> 5;          // 0..31
            int d4 = g & 31;
            xs[r * 32 + d4] =
                *reinterpret_cast<const float4*>(&x[(row0 + r) * DIM + d0 + 4 * d4]);
        }
        __syncthreads();
        // ---- compute: per d4: 4 W elems per lane + 8 uniform x float4 reads ----
#pragma unroll 4
        for (int d4 = 0; d4 < 32; ++d4) {
            int col = lane ^ d4;
            float w0 = wt[(4 * d4 + 0) * 64 + col];
            float w1 = wt[(4 * d4 + 1) * 64 + col];
            float w2 = wt[(4 * d4 + 2) * 64 + col];
            float w3 = wt[(4 * d4 + 3) * 64 + col];
#pragma unroll
            for (int r = 0; r < ROWS_PER_WAVE; ++r) {
                float4 xv = xs[(wrow0 + r) * 32 + d4];   // uniform addr -> broadcast
                acc[r] = fmaf(xv.x, w0, acc[r]);
                acc[r] = fmaf(xv.y, w1, acc[r]);
                acc[r] = fmaf(xv.z, w2, acc[r]);
                acc[r] = fmaf(xv.w, w3, acc[r]);
            }
        }
    }

    // ---- epilogue: softmax across 64 lanes (= experts), top-2 with tie->lowest idx ----
    float* out_vals = out;                    // [N][2] float
    float* out_idx  = out + N_ROWS * 2;       // [N][2] indices stored as float
    float* out_sc   = out + N_ROWS * 4;       // [N][64]

#pragma unroll
    for (int r = 0; r < ROWS_PER_WAVE; ++r) {
        const int n = row0 + wrow0 + r;
        float s = acc[r];
        float m = s;
#pragma unroll
        for (int off = 32; off; off >>= 1) m = fmaxf(m, __shfl_xor(m, off));
        float e = expf(s - m);
        float sum = e;
#pragma unroll
        for (int off = 32; off; off >>= 1) sum += __shfl_xor(sum, off);
        float p = e / sum;
        out_sc[n * 64 + lane] = p;

        // top-1 (max value, lowest index on tie)
        float v1 = p; int i1 = lane;
#pragma unroll
        for (int off = 32; off; off >>= 1) {
            float ov = __shfl_xor(v1, off);
            int   oi = __shfl_xor(i1, off);
            if (ov > v1 || (ov == v1 && oi < i1)) { v1 = ov; i1 = oi; }
        }
        // top-2: exclude i1
        float v2 = (lane == i1) ? -1.0f : p; int i2 = lane;
#pragma unroll
        for (int off = 32; off; off >>= 1) {
            float ov = __shfl_xor(v2, off);
            int   oi = __shfl_xor(i2, off);
            if (ov > v2 || (ov == v2 && oi < i2)) { v2 = ov; i2 = oi; }
        }
        if (lane == 0) {
            out_vals[n * 2 + 0] = v1;          // ROUTE_SCALE == 1.0
            out_vals[n * 2 + 1] = v2;
            out_idx[n * 2 + 0]  = (float)i1;
            out_idx[n * 2 + 1]  = (float)i2;
        }
    }
}

extern "C" void kernel_launch(void* const* d_in, const int* in_sizes, int n_in,
                              void* d_out, int out_size, void* d_ws, size_t ws_size,
                              hipStream_t stream)
{
    const float* x = (const float*)d_in[0];
    const float* w = (const float*)d_in[1];
    float* out = (float*)d_out;
    dim3 grid(N_ROWS / ROWS_PER_BLOCK);   // 512
    dim3 block(256);
    gate_kernel<<<grid, block, 0, stream>>>(x, w, out);
}

// Round 2
// 275.833 us; speedup vs baseline: 1.0396x; 1.0396x over previous
//
#include <hip/hip_runtime.h>
#include <math.h>

#define N_ROWS 16384
#define DIM 4096
#define NEXP 64
#define DT 64
#define NT (DIM / DT)                       // 64 k-tiles
#define WAVES 4
#define ROWS_PER_WAVE 8
#define ROWS_PER_BLOCK (WAVES * ROWS_PER_WAVE)   // 32
#define XSTR 68                             // row stride in floats (pad: bank stagger, 16B aligned)
#define WSTR 68

// top-k comparator: greater value wins; tie -> lower index (matches jax.lax.top_k)
__device__ __forceinline__ bool gtpair(float a, int ia, float b, int ib) {
    return (a > b) || (a == b && ia < ib);
}

// lane l: half h = l>>5 (processes rows 2r+h), le = l&31, experts {le, le+32}.
// One xs b128 read per row-pair serves both halves (2 distinct addrs, disjoint
// bank quads via stride 68) and feeds 8 FMA/lane.
__global__ __launch_bounds__(256, 2)
void gate_kernel(const float* __restrict__ x, const float* __restrict__ w,
                 float* __restrict__ out)
{
    __shared__ float wt[NEXP * WSTR];               // 17.0 KB
    __shared__ float xs[ROWS_PER_BLOCK * XSTR];     //  8.5 KB

    const int tid  = threadIdx.x;
    const int lane = tid & 63;
    const int wv   = tid >> 6;
    const int h    = lane >> 5;
    const int le   = lane & 31;
    const int row0 = blockIdx.x * ROWS_PER_BLOCK;

    float acc0[4] = {0.f, 0.f, 0.f, 0.f};   // expert le
    float acc1[4] = {0.f, 0.f, 0.f, 0.f};   // expert le + 32

    for (int t = 0; t < NT; ++t) {
        const int k0 = t * DT;
        __syncthreads();
        // stage W tile: 64 experts x 64 k = 1024 float4, 4 per thread (row-major, stride 68)
#pragma unroll
        for (int i = 0; i < 4; ++i) {
            int g = i * 256 + tid;
            int e = g >> 4, c4 = g & 15;
            float4 v = *reinterpret_cast<const float4*>(&w[(size_t)e * DIM + k0 + 4 * c4]);
            *reinterpret_cast<float4*>(&wt[e * WSTR + 4 * c4]) = v;
        }
        // stage x tile: 32 rows x 64 k = 512 float4, 2 per thread
#pragma unroll
        for (int i = 0; i < 2; ++i) {
            int g = i * 256 + tid;
            int rr = g >> 4, c4 = g & 15;
            float4 v = *reinterpret_cast<const float4*>(&x[(size_t)(row0 + rr) * DIM + k0 + 4 * c4]);
            *reinterpret_cast<float4*>(&xs[rr * XSTR + 4 * c4]) = v;
        }
        __syncthreads();

#pragma unroll
        for (int k4 = 0; k4 < DT / 4; ++k4) {
            float4 wA = *reinterpret_cast<const float4*>(&wt[le * WSTR + 4 * k4]);
            float4 wB = *reinterpret_cast<const float4*>(&wt[(le + 32) * WSTR + 4 * k4]);
#pragma unroll
            for (int r = 0; r < 4; ++r) {
                int rr = wv * ROWS_PER_WAVE + 2 * r + h;
                float4 xv = *reinterpret_cast<const float4*>(&xs[rr * XSTR + 4 * k4]);
                acc0[r] = fmaf(xv.x, wA.x, acc0[r]);
                acc0[r] = fmaf(xv.y, wA.y, acc0[r]);
                acc0[r] = fmaf(xv.z, wA.z, acc0[r]);
                acc0[r] = fmaf(xv.w, wA.w, acc0[r]);
                acc1[r] = fmaf(xv.x, wB.x, acc1[r]);
                acc1[r] = fmaf(xv.y, wB.y, acc1[r]);
                acc1[r] = fmaf(xv.z, wB.z, acc1[r]);
                acc1[r] = fmaf(xv.w, wB.w, acc1[r]);
            }
        }
    }

    // ---- epilogue: per-row softmax + top-2 across the 32 lanes of each half ----
    float* out_vals = out;                        // [N][2]
    float* out_idx  = out + (size_t)N_ROWS * 2;   // [N][2] (indices as float)
    float* out_sc   = out + (size_t)N_ROWS * 4;   // [N][64]

#pragma unroll
    for (int r = 0; r < 4; ++r) {
        const int n = row0 + wv * ROWS_PER_WAVE + 2 * r + h;
        float s0 = acc0[r], s1 = acc1[r];
        float m = fmaxf(s0, s1);
#pragma unroll
        for (int off = 16; off; off >>= 1) m = fmaxf(m, __shfl_xor(m, off));
        float e0 = expf(s0 - m), e1 = expf(s1 - m);
        float sum = e0 + e1;
#pragma unroll
        for (int off = 16; off; off >>= 1) sum += __shfl_xor(sum, off);
        float p0 = e0 / sum, p1 = e1 / sum;
        out_sc[(size_t)n * 64 + le]      = p0;
        out_sc[(size_t)n * 64 + le + 32] = p1;

        // local sorted pair, then butterfly merge over the half-wave
        float v1, v2; int i1, i2;
        if (gtpair(p0, le, p1, le + 32)) { v1 = p0; i1 = le;      v2 = p1; i2 = le + 32; }
        else                             { v1 = p1; i1 = le + 32; v2 = p0; i2 = le; }
#pragma unroll
        for (int off = 16; off; off >>= 1) {
            float o1 = __shfl_xor(v1, off); int oi1 = __shfl_xor(i1, off);
            float o2 = __shfl_xor(v2, off); int oi2 = __shfl_xor(i2, off);
            if (gtpair(o1, oi1, v1, i1)) {
                if (gtpair(v1, i1, o2, oi2)) { v2 = v1; i2 = i1; }
                else                         { v2 = o2; i2 = oi2; }
                v1 = o1; i1 = oi1;
            } else if (gtpair(o1, oi1, v2, i2)) {
                v2 = o1; i2 = oi1;
            }
        }
        if (le == 0) {
            out_vals[(size_t)n * 2 + 0] = v1;     // ROUTE_SCALE == 1.0
            out_vals[(size_t)n * 2 + 1] = v2;
            out_idx[(size_t)n * 2 + 0]  = (float)i1;
            out_idx[(size_t)n * 2 + 1]  = (float)i2;
        }
    }
}

extern "C" void kernel_launch(void* const* d_in, const int* in_sizes, int n_in,
                              void* d_out, int out_size, void* d_ws, size_t ws_size,
                              hipStream_t stream)
{
    const float* x = (const float*)d_in[0];
    const float* w = (const float*)d_in[1];
    float* out = (float*)d_out;
    dim3 grid(N_ROWS / ROWS_PER_BLOCK);   // 512
    dim3 block(256);
    gate_kernel<<<grid, block, 0, stream>>>(x, w, out);
}